// Round 20
// baseline (277.026 us; speedup 1.0000x reference)
//
#include <hip/hip_runtime.h>
#include <hip/hip_bf16.h>
#include <hip/hip_fp8.h>
#include <stdint.h>

#define B_   8
#define C_   512
#define NPIX 4096
#define VLDB 4160   // V row stride in BYTES: 65x64B (odd multiplier, r12 law)

typedef __attribute__((ext_vector_type(8))) short bf16x8;
typedef __attribute__((ext_vector_type(4))) float f32x4;

__device__ __forceinline__ uint32_t pk2(float a, float b) {
    union { __hip_bfloat162 h; uint32_t u; } c;
    c.h = __float22bfloat162_rn(make_float2(a, b));
    return c.u;
}

// raw v_exp_f32 (2^x); inputs small and clamped.
__device__ __forceinline__ float fexp2(float x) {
#if __has_builtin(__builtin_amdgcn_exp2f)
    return __builtin_amdgcn_exp2f(x);
#else
    return exp2f(x);
#endif
}

template<bool HI>
__device__ __forceinline__ uint32_t pk_fp8(float a, float b, uint32_t old) {
#if __has_builtin(__builtin_amdgcn_cvt_pk_fp8_f32)
    return __builtin_amdgcn_cvt_pk_fp8_f32(a, b, old, HI);
#else
    union { __hip_fp8_storage_t s[4]; uint32_t u; } r; r.u = old;
    r.s[HI * 2 + 0] = __hip_cvt_float_to_fp8(a, __HIP_SATFINITE, __HIP_E4M3);
    r.s[HI * 2 + 1] = __hip_cvt_float_to_fp8(b, __HIP_SATFINITE, __HIP_E4M3);
    return r.u;
#endif
}
__device__ __forceinline__ uint8_t f2fp8(float a) {
#if __has_builtin(__builtin_amdgcn_cvt_pk_fp8_f32)
    uint32_t u = __builtin_amdgcn_cvt_pk_fp8_f32(a, 0.f, 0u, false);
    return (uint8_t)(u & 0xFF);
#else
    return __hip_cvt_float_to_fp8(a, __HIP_SATFINITE, __HIP_E4M3);
#endif
}

// d-permutation within a 64-elem row so one 16B/lane load covers both kk frags
__device__ __forceinline__ int perm64(int d) {
    return ((d >> 3) & 3) * 16 + ((d >> 5) << 3) + (d & 7);
}

// ---------------- q/k projection: fp8 out[b][n][perm(o)], 64B rows ---------
__global__ __launch_bounds__(256, 2) void projqk_kernel(
    const float* __restrict__ X, const float* __restrict__ W,
    const float* __restrict__ bias, uint8_t* __restrict__ outp,
    float scale)
{
    __shared__ char xt[64 * 128];
    const int b  = blockIdx.z;
    const int n0 = blockIdx.x * 64;
    const int t = threadIdx.x, w = t >> 6, l = t & 63;
    const int l15 = l & 15, lg = l >> 4;
    const float* Xb = X + (size_t)b * C_ * NPIX + n0;

    f32x4 acc[4] = {};

    for (int cc = 0; cc < C_; cc += 64) {
        __syncthreads();
        #pragma unroll
        for (int i = 0; i < 16; i += 2) {
            int c = w * 16 + i;
            float f0 = Xb[(size_t)(cc + c) * NPIX + l];
            float f1 = Xb[(size_t)(cc + c + 1) * NPIX + l];
            uint32_t pair = pk2(f0, f1);
            int byte = (l * 128 + c * 2) ^ ((l & 7) << 4);
            *(uint32_t*)(xt + byte) = pair;
        }
        __syncthreads();
        #pragma unroll
        for (int kk = 0; kk < 2; kk++) {
            int o  = w * 16 + l15;
            int cb = cc + kk * 32 + lg * 8;
            float4 wa = *(const float4*)&W[(size_t)o * C_ + cb];
            float4 wb = *(const float4*)&W[(size_t)o * C_ + cb + 4];
            union { bf16x8 v; uint32_t u[4]; } afu;
            afu.u[0] = pk2(wa.x, wa.y); afu.u[1] = pk2(wa.z, wa.w);
            afu.u[2] = pk2(wb.x, wb.y); afu.u[3] = pk2(wb.z, wb.w);
            #pragma unroll
            for (int jt = 0; jt < 4; jt++) {
                int n = jt * 16 + l15;
                int byte = (n * 128 + (kk * 32 + lg * 8) * 2) ^ ((n & 7) << 4);
                bf16x8 bfr = *(bf16x8*)(xt + byte);
                acc[jt] = __builtin_amdgcn_mfma_f32_16x16x32_bf16(afu.v, bfr, acc[jt], 0, 0, 0);
            }
        }
    }
    int og = w * 16 + lg * 4;
    #pragma unroll
    for (int jt = 0; jt < 4; jt++) {
        int n = n0 + jt * 16 + l15;
        #pragma unroll
        for (int r = 0; r < 4; r++) {
            float v = (acc[jt][r] + bias[og + r]) * scale;
            outp[((size_t)b * NPIX + n) * 64 + perm64(og + r)] = f2fp8(v);
        }
    }
}

// ---------------- V projection: read z once; fp8 out (r18) -----------------
__global__ __launch_bounds__(256, 2) void projv_kernel(
    const float* __restrict__ X, const float* __restrict__ W,
    const float* __restrict__ bias, uint8_t* __restrict__ outp)
{
    __shared__ char xt[64 * 1024];
    const int b  = blockIdx.z;
    const int n0 = blockIdx.x * 64;
    const int t = threadIdx.x, w = t >> 6, l = t & 63;
    const int l15 = l & 15, lg = l >> 4;
    const float* Xb = X + (size_t)b * C_ * NPIX + n0;

    for (int cc = 0; cc < C_; cc += 64) {
        #pragma unroll
        for (int i = 0; i < 16; i += 2) {
            int c = cc + w * 16 + i;
            float f0 = Xb[(size_t)c * NPIX + l];
            float f1 = Xb[(size_t)(c + 1) * NPIX + l];
            uint32_t pair = pk2(f0, f1);
            int byte = (l * 1024 + c * 2) ^ ((l & 7) << 4);
            *(uint32_t*)(xt + byte) = pair;
        }
    }
    __syncthreads();

    #pragma unroll 1
    for (int o0 = 0; o0 < C_; o0 += 64) {
        f32x4 acc[4] = {};
        #pragma unroll 1
        for (int cc = 0; cc < C_; cc += 64) {
            #pragma unroll
            for (int kk = 0; kk < 2; kk++) {
                int o  = o0 + w * 16 + l15;
                int cb = cc + kk * 32 + lg * 8;
                float4 wa = *(const float4*)&W[(size_t)o * C_ + cb];
                float4 wb = *(const float4*)&W[(size_t)o * C_ + cb + 4];
                union { bf16x8 v; uint32_t u[4]; } afu;
                afu.u[0] = pk2(wa.x, wa.y); afu.u[1] = pk2(wa.z, wa.w);
                afu.u[2] = pk2(wb.x, wb.y); afu.u[3] = pk2(wb.z, wb.w);
                #pragma unroll
                for (int jt = 0; jt < 4; jt++) {
                    int n = jt * 16 + l15;
                    int byte = (n * 1024 + cb * 2) ^ ((n & 7) << 4);
                    bf16x8 bfr = *(bf16x8*)(xt + byte);
                    acc[jt] = __builtin_amdgcn_mfma_f32_16x16x32_bf16(afu.v, bfr, acc[jt], 0, 0, 0);
                }
            }
        }
        int og = o0 + w * 16 + lg * 4;
        #pragma unroll
        for (int jt = 0; jt < 4; jt++) {
            int j6 = jt * 16 + l15;
            int pos = perm64(j6);
            #pragma unroll
            for (int r = 0; r < 4; r++) {
                float v = (acc[jt][r] + bias[og + r]) * 64.0f;  // fp8 mid-range
                outp[((size_t)b * C_ + og + r) * (size_t)VLDB + (size_t)(n0 >> 6) * 64 + pos] = f2fp8(v);
            }
        }
    }
}

// ---------------- fused flash attention: QROWS=128, V LDS-dedup, fp8 QK ----
// Grid 512 = 8b x 32qt x 2cb; 8 waves (iq 2 x cq 4). Wave: 64 i x 64 c.
// V staged once/block/step into LDS (reg round-trip, 2 bufs, write post-
// barrier) -> V traffic 1GB->512MB. Q/K fp8 (q x16*log2e, k x16; exp2 arg
// /256) -> K bytes halved. P 128x64 fp8, 3 bufs, pre-barrier write.
__global__ __launch_bounds__(512, 1) void attn_kernel(
    const uint8_t* __restrict__ qT, const uint8_t* __restrict__ kT,
    const uint8_t* __restrict__ vB, const float* __restrict__ X,
    const float* __restrict__ gamma_p, float* __restrict__ out)
{
    __shared__ char  Pl[3][128 * 64];   // P[i][j] fp8, byte=i*64+j ^ ((i&7)<<3)
    __shared__ char  Vl[2][16384];      // V tile 256c x 64j fp8, swizzled
    __shared__ float lsum[128][5];

    const int id = blockIdx.x;
    const int b  = id & 7;              // batch pinned to XCD
    const int rr = id >> 3;
    const int qt = rr & 31, cb = rr >> 5;
    const int i0 = qt * 128;

    const int t = threadIdx.x, w = t >> 6, l = t & 63;
    const int iq = w >> 2, cq = w & 3;
    const int l15 = l & 15, lg = l >> 4;

    auto barrier_lds = [&]() {
        asm volatile("s_waitcnt lgkmcnt(0)" ::: "memory");
        __builtin_amdgcn_s_barrier();
    };

    // Q fragments (fp8, d-permuted rows): 16B covers both kk chunks
    ulong2 qf[4];
    {
        const uint8_t* qbase = qT + ((size_t)b * NPIX + i0 + iq * 64) * 64;
        #pragma unroll
        for (int it = 0; it < 4; it++)
            qf[it] = *(const ulong2*)(qbase + (it * 16 + l15) * 64 + lg * 16);
    }

    f32x4 oacc[4][4] = {};    // [ct][it] : O^T[c][i]
    float l_part[4] = {0.f, 0.f, 0.f, 0.f};

    // K row pointer: this wave's j-slice = cq*16 + l15 (64B fp8 rows)
    const uint8_t* kROW = kT + (size_t)b * NPIX * 64 + (size_t)(cq * 16 + l15) * 64 + lg * 16;
    // V block slice base (256 c rows)
    const uint8_t* vblk = vB + ((size_t)b * C_ + cb * 256) * (size_t)VLDB;

    // V staging geometry: 16KB/step, thread t handles granules t and 512+t
    const int g0 = t, g1 = 512 + t;
    const int row0 = g0 >> 2, cq0 = g0 & 3;
    const int row1 = g1 >> 2, cq1 = g1 & 3;
    const uint8_t* vsrc0 = vblk + (size_t)row0 * VLDB + cq0 * 16;
    const uint8_t* vsrc1 = vblk + (size_t)row1 * VLDB + cq1 * 16;
    const int vdst0 = row0 * 64 + ((cq0 ^ (row0 & 3)) * 16);
    const int vdst1 = row1 * 64 + ((cq1 ^ (row1 & 3)) * 16);

    ulong2 kv, vt0, vt1;
    f32x4 s[4];

    auto loadK = [&](int step) {
        kv = *(const ulong2*)(kROW + (size_t)step * 4096);
    };
    auto vstage_load = [&](int step) {
        vt0 = *(const ulong2*)(vsrc0 + (size_t)step * 64);
        vt1 = *(const ulong2*)(vsrc1 + (size_t)step * 64);
    };
    auto vstage_write = [&](int buf) {
        *(ulong2*)(Vl[buf] + vdst0) = vt0;
        *(ulong2*)(Vl[buf] + vdst1) = vt1;
    };
    auto QK = [&]() {
        #pragma unroll
        for (int it = 0; it < 4; it++) s[it] = f32x4{0.f, 0.f, 0.f, 0.f};
        __builtin_amdgcn_s_setprio(1);
        #pragma unroll
        for (int it = 0; it < 4; it++)
            s[it] = __builtin_amdgcn_mfma_f32_16x16x32_fp8_fp8((long)kv.x, (long)qf[it].x, s[it], 0, 0, 0);
        #pragma unroll
        for (int it = 0; it < 4; it++)
            s[it] = __builtin_amdgcn_mfma_f32_16x16x32_fp8_fp8((long)kv.y, (long)qf[it].y, s[it], 0, 0, 0);
        __builtin_amdgcn_s_setprio(0);
    };
    // P = exp2(clamp(s/256)); f32 row-sums; fp8 pack -> LDS
    auto PcomputeWrite = [&](char* Pn) {
        #pragma unroll
        for (int it = 0; it < 4; it++) {
            float e0 = fexp2(fminf(s[it][0] * 0.00390625f, 60.f));
            float e1 = fexp2(fminf(s[it][1] * 0.00390625f, 60.f));
            float e2 = fexp2(fminf(s[it][2] * 0.00390625f, 60.f));
            float e3 = fexp2(fminf(s[it][3] * 0.00390625f, 60.f));
            l_part[it] += (e0 + e1) + (e2 + e3);
            uint32_t p4 = pk_fp8<false>(e0, e1, 0u);
            p4 = pk_fp8<true>(e2, e3, p4);
            int i = iq * 64 + it * 16 + l15;
            int byte = (i * 64 + cq * 16 + lg * 4) ^ ((i & 7) << 3);
            *(uint32_t*)(Pn + byte) = p4;
        }
    };
    auto PV = [&](const char* P, const char* V) {
        __builtin_amdgcn_s_setprio(1);
        ulong2 vf[4];
        #pragma unroll
        for (int ct = 0; ct < 4; ct++) {
            int row = cq * 64 + ct * 16 + l15;
            vf[ct] = *(const ulong2*)(V + row * 64 + ((lg ^ (row & 3)) * 16));
        }
        #pragma unroll
        for (int kk = 0; kk < 2; kk++) {
            long pb[4];
            #pragma unroll
            for (int it = 0; it < 4; it++) {
                int i = iq * 64 + it * 16 + l15;
                int byte = (i * 64 + kk * 32 + lg * 8) ^ ((i & 7) << 3);
                pb[it] = *(const long*)(P + byte);
            }
            #pragma unroll
            for (int ct = 0; ct < 4; ct++) {
                long v8 = (long)(kk ? vf[ct].y : vf[ct].x);
                #pragma unroll
                for (int it = 0; it < 4; it++)
                    oacc[ct][it] = __builtin_amdgcn_mfma_f32_16x16x32_fp8_fp8(v8, pb[it], oacc[ct][it], 0, 0, 0);
            }
        }
        __builtin_amdgcn_s_setprio(0);
    };

    // ---- prologue ----
    loadK(0);
    vstage_load(0);
    QK();                     // S(0)
    loadK(1);
    PcomputeWrite(Pl[0]);     // P(0)
    vstage_write(0);          // V(0) -> buf0 (no readers yet)
    vstage_load(1);
    QK();                     // S(1)
    loadK(2);
    PcomputeWrite(Pl[1]);     // P(1)

    char* Pprev = Pl[0];
    char* Pcur  = Pl[1];
    char* Pnext = Pl[2];

    // ---- steady state: 1 LDS-only barrier per 64-j step (64 total) ----
    #pragma unroll 1
    for (int jt_ = 1; jt_ < 64; ++jt_) {
        barrier_lds();
        PV(Pprev, Vl[(jt_ - 1) & 1]);   // P(t-1), V(t-1)
        vstage_write(jt_ & 1);          // V(t) (buf last read pre-barrier)
        if (jt_ < 63) {
            vstage_load(jt_ + 1);
            QK();                       // S(t+1), kv = K(t+1)
            if (jt_ < 62) loadK(jt_ + 2);
            PcomputeWrite(Pnext);       // P(t+1)
        }
        char* tmp = Pprev; Pprev = Pcur; Pcur = Pnext; Pnext = tmp;
    }
    barrier_lds();
    PV(Pprev, Vl[1]);                   // P(63), V(63)

    // ---- final l reduction ----
    #pragma unroll
    for (int it = 0; it < 4; it++) {
        float v = l_part[it];
        v += __shfl_xor(v, 16);
        v += __shfl_xor(v, 32);
        if (lg == 0) lsum[iq * 64 + it * 16 + l15][cq] = v;
    }
    __syncthreads();

    // ---- epilogue: out = gamma * (O/(64 l)) + x ----
    float gamma = gamma_p[0];
    float rl[4];
    #pragma unroll
    for (int it = 0; it < 4; it++) {
        int i = iq * 64 + it * 16 + l15;
        rl[it] = 1.0f / (64.0f * ((lsum[i][0] + lsum[i][1]) + (lsum[i][2] + lsum[i][3])));
    }
    #pragma unroll
    for (int ct = 0; ct < 4; ct++)
        #pragma unroll
        for (int r = 0; r < 4; r++) {
            int c = cb * 256 + cq * 64 + ct * 16 + lg * 4 + r;
            #pragma unroll
            for (int it = 0; it < 4; it++) {
                int n = i0 + iq * 64 + it * 16 + l15;
                size_t idx = ((size_t)b * C_ + c) * NPIX + n;
                out[idx] = gamma * (oacc[ct][it][r] * rl[it]) + X[idx];
            }
        }
}

extern "C" void kernel_launch(void* const* d_in, const int* in_sizes, int n_in,
                              void* d_out, int out_size, void* d_ws, size_t ws_size,
                              hipStream_t stream) {
    const float* x     = (const float*)d_in[0];
    const float* y     = (const float*)d_in[1];
    const float* z     = (const float*)d_in[2];
    const float* Wq    = (const float*)d_in[3];
    const float* bq    = (const float*)d_in[4];
    const float* Wk    = (const float*)d_in[5];
    const float* bk    = (const float*)d_in[6];
    const float* Wv    = (const float*)d_in[7];
    const float* bv    = (const float*)d_in[8];
    const float* gamma = (const float*)d_in[9];
    float* out = (float*)d_out;

    uint8_t* qT = (uint8_t*)d_ws;                         // [8][4096][64] fp8 perm
    uint8_t* kT = qT + (size_t)B_ * NPIX * 64;            // [8][4096][64] fp8 perm
    uint8_t* vb = kT + (size_t)B_ * NPIX * 64;            // [8][512] x VLDB, fp8 perm

    // q x 16*log2e, k x 16 (exp2 arg rescaled by 1/256 in-kernel); V x 64
    projqk_kernel<<<dim3(64, 1, 8), dim3(256), 0, stream>>>(x, Wq, bq, qT, 23.083120654223414f);
    projqk_kernel<<<dim3(64, 1, 8), dim3(256), 0, stream>>>(y, Wk, bk, kT, 16.0f);
    projv_kernel <<<dim3(64, 1, 8), dim3(256), 0, stream>>>(z, Wv, bv, vb);
    attn_kernel  <<<dim3(512), dim3(512), 0, stream>>>(qT, kT, vb, x, gamma, out);
}

// Round 21
// 257.578 us; speedup vs baseline: 1.0755x; 1.0755x over previous
//
#include <hip/hip_runtime.h>
#include <hip/hip_bf16.h>
#include <hip/hip_fp8.h>
#include <stdint.h>

#define B_   8
#define C_   512
#define NPIX 4096
#define VLDB 4160   // V row stride in BYTES: 65x64B (odd multiplier, r12 law)

typedef __attribute__((ext_vector_type(8))) short bf16x8;
typedef __attribute__((ext_vector_type(4))) float f32x4;

__device__ __forceinline__ uint16_t f2bf(float f) {
    union { float f; uint32_t u; } v; v.f = f;
    uint32_t u = v.u;
    return (uint16_t)((u + 0x7FFFu + ((u >> 16) & 1u)) >> 16);
}

__device__ __forceinline__ uint32_t pk2(float a, float b) {
    union { __hip_bfloat162 h; uint32_t u; } c;
    c.h = __float22bfloat162_rn(make_float2(a, b));
    return c.u;
}

// raw v_exp_f32 (2^x); inputs small and clamped.
__device__ __forceinline__ float fexp2(float x) {
#if __has_builtin(__builtin_amdgcn_exp2f)
    return __builtin_amdgcn_exp2f(x);
#else
    return exp2f(x);
#endif
}

template<bool HI>
__device__ __forceinline__ uint32_t pk_fp8(float a, float b, uint32_t old) {
#if __has_builtin(__builtin_amdgcn_cvt_pk_fp8_f32)
    return __builtin_amdgcn_cvt_pk_fp8_f32(a, b, old, HI);
#else
    union { __hip_fp8_storage_t s[4]; uint32_t u; } r; r.u = old;
    r.s[HI * 2 + 0] = __hip_cvt_float_to_fp8(a, __HIP_SATFINITE, __HIP_E4M3);
    r.s[HI * 2 + 1] = __hip_cvt_float_to_fp8(b, __HIP_SATFINITE, __HIP_E4M3);
    return r.u;
#endif
}
__device__ __forceinline__ uint8_t f2fp8(float a) {
#if __has_builtin(__builtin_amdgcn_cvt_pk_fp8_f32)
    uint32_t u = __builtin_amdgcn_cvt_pk_fp8_f32(a, 0.f, 0u, false);
    return (uint8_t)(u & 0xFF);
#else
    return __hip_cvt_float_to_fp8(a, __HIP_SATFINITE, __HIP_E4M3);
#endif
}

// j-permutation within a 64-elem row so one 16B/lane load covers both kk frags
__device__ __forceinline__ int perm64(int d) {
    return ((d >> 3) & 3) * 16 + ((d >> 5) << 3) + (d & 7);
}

// ---------------- W -> bf16 pre-convert (once; halves projv W traffic) -----
__global__ __launch_bounds__(256, 4) void convw_kernel(
    const float* __restrict__ W, uint16_t* __restrict__ Wb)
{
    int i = (blockIdx.x * 256 + threadIdx.x) * 8;
    float4 a = *(const float4*)&W[i];
    float4 b = *(const float4*)&W[i + 4];
    union { bf16x8 v; uint32_t u[4]; } r;
    r.u[0] = pk2(a.x, a.y); r.u[1] = pk2(a.z, a.w);
    r.u[2] = pk2(b.x, b.y); r.u[3] = pk2(b.z, b.w);
    *(bf16x8*)&Wb[i] = r.v;
}

// ---------------- q/k projection: bf16 out[b][n][o], O=64 (r19) ------------
__global__ __launch_bounds__(256, 2) void proj_kernel(
    const float* __restrict__ X, const float* __restrict__ W,
    const float* __restrict__ bias, uint16_t* __restrict__ out,
    float scale)
{
    __shared__ char xt[64 * 128];
    const int b  = blockIdx.z;
    const int n0 = blockIdx.x * 64;
    const int t = threadIdx.x, w = t >> 6, l = t & 63;
    const int l15 = l & 15, lg = l >> 4;
    const float* Xb = X + (size_t)b * C_ * NPIX + n0;

    f32x4 acc[4] = {};

    for (int cc = 0; cc < C_; cc += 64) {
        __syncthreads();
        #pragma unroll
        for (int i = 0; i < 16; i += 2) {
            int c = w * 16 + i;
            float f0 = Xb[(size_t)(cc + c) * NPIX + l];
            float f1 = Xb[(size_t)(cc + c + 1) * NPIX + l];
            uint32_t pair = pk2(f0, f1);
            int byte = (l * 128 + c * 2) ^ ((l & 7) << 4);
            *(uint32_t*)(xt + byte) = pair;
        }
        __syncthreads();
        #pragma unroll
        for (int kk = 0; kk < 2; kk++) {
            int o  = w * 16 + l15;
            int cb = cc + kk * 32 + lg * 8;
            float4 wa = *(const float4*)&W[(size_t)o * C_ + cb];
            float4 wb = *(const float4*)&W[(size_t)o * C_ + cb + 4];
            union { bf16x8 v; uint32_t u[4]; } afu;
            afu.u[0] = pk2(wa.x, wa.y); afu.u[1] = pk2(wa.z, wa.w);
            afu.u[2] = pk2(wb.x, wb.y); afu.u[3] = pk2(wb.z, wb.w);
            #pragma unroll
            for (int jt = 0; jt < 4; jt++) {
                int n = jt * 16 + l15;
                int byte = (n * 128 + (kk * 32 + lg * 8) * 2) ^ ((n & 7) << 4);
                bf16x8 bfr = *(bf16x8*)(xt + byte);
                acc[jt] = __builtin_amdgcn_mfma_f32_16x16x32_bf16(afu.v, bfr, acc[jt], 0, 0, 0);
            }
        }
    }
    int og = w * 16 + lg * 4;
    #pragma unroll
    for (int jt = 0; jt < 4; jt++) {
        int n = n0 + jt * 16 + l15;
        #pragma unroll
        for (int r = 0; r < 4; r++) {
            float v = (acc[jt][r] + bias[og + r]) * scale;
            out[((size_t)b * NPIX + n) * 64 + og + r] = f2bf(v);
        }
    }
}

// ---------------- V projection: 2 n-tiles/block, bf16 W --------------------
// Old projv: 512 blocks x 1MB fp32 W re-read = 512MB W traffic (~78us at the
// ~6cyc/64B-line/CU request equilibrium). New: 256 blocks, BOTH z-tiles
// staged (128KB LDS), W (bf16, pre-converted) chunk loaded once per (o,cc)
// and reused for both tiles -> W traffic 128MB. z read-once unchanged.
__global__ __launch_bounds__(256, 1) void projv_kernel(
    const float* __restrict__ X, const uint16_t* __restrict__ Wb,
    const float* __restrict__ bias, uint8_t* __restrict__ outp)
{
    __shared__ char xt[2][64 * 1024];   // 128KB: two [64n][512c] bf16 tiles
    const int b  = blockIdx.z;
    const int ng = blockIdx.x;          // n-tiles 2*ng, 2*ng+1
    const int t = threadIdx.x, w = t >> 6, l = t & 63;
    const int l15 = l & 15, lg = l >> 4;

    #pragma unroll
    for (int nt = 0; nt < 2; nt++) {
        const float* Xb = X + (size_t)b * C_ * NPIX + (ng * 2 + nt) * 64;
        for (int cc = 0; cc < C_; cc += 64) {
            #pragma unroll
            for (int i = 0; i < 16; i += 2) {
                int c = cc + w * 16 + i;
                float f0 = Xb[(size_t)c * NPIX + l];
                float f1 = Xb[(size_t)(c + 1) * NPIX + l];
                uint32_t pair = pk2(f0, f1);
                int byte = (l * 1024 + c * 2) ^ ((l & 7) << 4);
                *(uint32_t*)(xt[nt] + byte) = pair;
            }
        }
    }
    __syncthreads();

    #pragma unroll 1
    for (int o0 = 0; o0 < C_; o0 += 64) {
        f32x4 acc[2][4] = {};
        #pragma unroll 1
        for (int cc = 0; cc < C_; cc += 64) {
            #pragma unroll
            for (int kk = 0; kk < 2; kk++) {
                int o  = o0 + w * 16 + l15;
                int cb = cc + kk * 32 + lg * 8;
                bf16x8 af = *(const bf16x8*)&Wb[(size_t)o * C_ + cb];
                #pragma unroll
                for (int nt = 0; nt < 2; nt++)
                    #pragma unroll
                    for (int jt = 0; jt < 4; jt++) {
                        int n = jt * 16 + l15;
                        int byte = (n * 1024 + cb * 2) ^ ((n & 7) << 4);
                        bf16x8 bfr = *(bf16x8*)(xt[nt] + byte);
                        acc[nt][jt] = __builtin_amdgcn_mfma_f32_16x16x32_bf16(af, bfr, acc[nt][jt], 0, 0, 0);
                    }
            }
        }
        int og = o0 + w * 16 + lg * 4;
        #pragma unroll
        for (int nt = 0; nt < 2; nt++) {
            int n0 = (ng * 2 + nt) * 64;
            #pragma unroll
            for (int jt = 0; jt < 4; jt++) {
                int j6 = jt * 16 + l15;
                int pos = perm64(j6);
                #pragma unroll
                for (int r = 0; r < 4; r++) {
                    float v = (acc[nt][jt][r] + bias[og + r]) * 64.0f;  // fp8 mid-range
                    outp[((size_t)b * C_ + og + r) * (size_t)VLDB + (size_t)(n0 >> 6) * 64 + pos] = f2fp8(v);
                }
            }
        }
    }
}

// ---------------- fused flash attention (r19, frozen) ----------------------
// 8-wave block owns q-tile x all 512 ch; softmax once; KVBLK=128 (32 steps);
// fp8 V+P, bf16 QK; lgkm-only barrier; at the L1-request equilibrium ~180us.
__global__ __launch_bounds__(512, 1) void attn_kernel(
    const uint16_t* __restrict__ qT, const uint16_t* __restrict__ kT,
    const uint8_t* __restrict__ vB, const float* __restrict__ X,
    const float* __restrict__ gamma_p, float* __restrict__ out)
{
    __shared__ char  Pl[3][64 * 128];   // P[i][j] fp8, byte=i*128+j ^ ((i&15)<<3)
    __shared__ float lsum[64][9];

    const int id = blockIdx.x;
    const int b  = id & 7;
    const int qt = id >> 3;
    const int i0 = qt * 64;

    const int t = threadIdx.x, w = t >> 6, l = t & 63;
    const int l15 = l & 15, lg = l >> 4;
    const int c0 = w * 64;

    auto barrier_lds = [&]() {
        asm volatile("s_waitcnt lgkmcnt(0)" ::: "memory");
        __builtin_amdgcn_s_barrier();
    };

    bf16x8 q8[4][2];
    #pragma unroll
    for (int it = 0; it < 4; it++)
        #pragma unroll
        for (int kk = 0; kk < 2; kk++)
            q8[it][kk] = *(const bf16x8*)&qT[((size_t)b * NPIX + i0 + it*16 + l15) * 64 + kk*32 + lg*8];

    f32x4 oacc[4][4] = {};
    float l_part[4] = {0.f, 0.f, 0.f, 0.f};

    const uint16_t* kTb = kT + (size_t)b * NPIX * 64;
    const uint8_t*  vBb = vB + ((size_t)b * C_ + c0) * (size_t)VLDB + lg * 16;
    const uint16_t* kROW = kTb + (size_t)(w * 16 + l15) * 64 + lg * 8;

    int vrowB[4];
    #pragma unroll
    for (int ct = 0; ct < 4; ct++) vrowB[ct] = (ct * 16 + l15) * VLDB;

    bf16x8 k8[2];
    ulong2 vreg[8];
    f32x4 s[4];

    auto loadK = [&](int step) {
        const uint16_t* p = kROW + (size_t)step * (128 * 64);
        k8[0] = *(const bf16x8*)p;
        k8[1] = *(const bf16x8*)(p + 32);
    };
    auto loadV = [&](int step) {
        const uint8_t* p = vBb + (size_t)step * 128;
        #pragma unroll
        for (int jh = 0; jh < 2; jh++)
            #pragma unroll
            for (int ct = 0; ct < 4; ct++)
                vreg[jh*4+ct] = *(const ulong2*)(p + vrowB[ct] + jh * 64);
    };
    auto QK = [&]() {
        #pragma unroll
        for (int it = 0; it < 4; it++) s[it] = f32x4{0.f, 0.f, 0.f, 0.f};
        __builtin_amdgcn_s_setprio(1);
        #pragma unroll
        for (int kk = 0; kk < 2; kk++)
            #pragma unroll
            for (int it = 0; it < 4; it++)
                s[it] = __builtin_amdgcn_mfma_f32_16x16x32_bf16(k8[kk], q8[it][kk], s[it], 0, 0, 0);
        __builtin_amdgcn_s_setprio(0);
    };
    auto PcomputeWrite = [&](char* Pn) {
        #pragma unroll
        for (int it = 0; it < 4; it++) {
            float e0 = fexp2(fminf(s[it][0], 60.f));
            float e1 = fexp2(fminf(s[it][1], 60.f));
            float e2 = fexp2(fminf(s[it][2], 60.f));
            float e3 = fexp2(fminf(s[it][3], 60.f));
            l_part[it] += (e0 + e1) + (e2 + e3);
            uint32_t p4 = pk_fp8<false>(e0, e1, 0u);
            p4 = pk_fp8<true>(e2, e3, p4);
            int i = it * 16 + l15;
            int byte = (i * 128 + w * 16 + lg * 4) ^ ((i & 15) << 3);
            *(uint32_t*)(Pn + byte) = p4;
        }
    };
    auto PV = [&](const char* P) {
        __builtin_amdgcn_s_setprio(1);
        #pragma unroll
        for (int jh = 0; jh < 2; jh++)
            #pragma unroll
            for (int kk = 0; kk < 2; kk++) {
                long pb[4];
                #pragma unroll
                for (int it = 0; it < 4; it++) {
                    int i = it * 16 + l15;
                    int byte = (i * 128 + jh * 64 + kk * 32 + lg * 8) ^ ((i & 15) << 3);
                    pb[it] = *(const long*)(P + byte);
                }
                #pragma unroll
                for (int ct = 0; ct < 4; ct++) {
                    long v8 = (long)(kk ? vreg[jh*4+ct].y : vreg[jh*4+ct].x);
                    #pragma unroll
                    for (int it = 0; it < 4; it++)
                        oacc[ct][it] = __builtin_amdgcn_mfma_f32_16x16x32_fp8_fp8(v8, pb[it], oacc[ct][it], 0, 0, 0);
                }
            }
        __builtin_amdgcn_s_setprio(0);
    };

    // ---- prologue ----
    loadK(0);
    loadV(0);
    QK();
    loadK(1);
    PcomputeWrite(Pl[0]);
    QK();
    loadK(2);
    PcomputeWrite(Pl[1]);

    char* Pprev = Pl[0];
    char* Pcur  = Pl[1];
    char* Pnext = Pl[2];

    #pragma unroll 1
    for (int jt_ = 1; jt_ < 32; ++jt_) {
        barrier_lds();
        PV(Pprev);
        loadV(jt_);
        if (jt_ < 31) {
            QK();
            if (jt_ < 30) loadK(jt_ + 2);
            PcomputeWrite(Pnext);
        }
        char* tmp = Pprev; Pprev = Pcur; Pcur = Pnext; Pnext = tmp;
    }
    barrier_lds();
    PV(Pprev);

    #pragma unroll
    for (int it = 0; it < 4; it++) {
        float v = l_part[it];
        v += __shfl_xor(v, 16);
        v += __shfl_xor(v, 32);
        if (lg == 0) lsum[it * 16 + l15][w] = v;
    }
    __syncthreads();

    float gamma = gamma_p[0];
    float rl[4];
    #pragma unroll
    for (int it = 0; it < 4; it++) {
        int i = it * 16 + l15;
        float lt = ((lsum[i][0] + lsum[i][1]) + (lsum[i][2] + lsum[i][3]))
                 + ((lsum[i][4] + lsum[i][5]) + (lsum[i][6] + lsum[i][7]));
        rl[it] = 1.0f / (64.0f * lt);
    }
    #pragma unroll
    for (int ct = 0; ct < 4; ct++)
        #pragma unroll
        for (int r = 0; r < 4; r++) {
            int c = c0 + ct * 16 + lg * 4 + r;
            #pragma unroll
            for (int it = 0; it < 4; it++) {
                int n = i0 + it * 16 + l15;
                size_t idx = ((size_t)b * C_ + c) * NPIX + n;
                out[idx] = gamma * (oacc[ct][it][r] * rl[it]) + X[idx];
            }
        }
}

extern "C" void kernel_launch(void* const* d_in, const int* in_sizes, int n_in,
                              void* d_out, int out_size, void* d_ws, size_t ws_size,
                              hipStream_t stream) {
    const float* x     = (const float*)d_in[0];
    const float* y     = (const float*)d_in[1];
    const float* z     = (const float*)d_in[2];
    const float* Wq    = (const float*)d_in[3];
    const float* bq    = (const float*)d_in[4];
    const float* Wk    = (const float*)d_in[5];
    const float* bk    = (const float*)d_in[6];
    const float* Wv    = (const float*)d_in[7];
    const float* bv    = (const float*)d_in[8];
    const float* gamma = (const float*)d_in[9];
    float* out = (float*)d_out;

    uint16_t* qT  = (uint16_t*)d_ws;                        // [8][4096][64] bf16
    uint16_t* kT  = qT + (size_t)B_ * NPIX * 64;            // [8][4096][64] bf16
    uint8_t*  vb  = (uint8_t*)(kT + (size_t)B_ * NPIX * 64);// [8][512] x VLDB, fp8
    uint16_t* Wvb = (uint16_t*)(vb + (size_t)B_ * C_ * VLDB); // [512][512] bf16

    convw_kernel<<<dim3(128), dim3(256), 0, stream>>>(Wv, Wvb);
    // q pre-scaled by log2(e); V pre-scaled by 64 (fp8 mid-range)
    proj_kernel <<<dim3(64, 1, 8), dim3(256), 0, stream>>>(x, Wq, bq, qT, 1.4426950408889634f);
    proj_kernel <<<dim3(64, 1, 8), dim3(256), 0, stream>>>(y, Wk, bk, kT, 1.0f);
    projv_kernel<<<dim3(32, 1, 8), dim3(256), 0, stream>>>(z, Wvb, bv, vb);
    attn_kernel <<<dim3(512), dim3(512), 0, stream>>>(qT, kT, vb, x, gamma, out);
}

// Round 22
// 245.597 us; speedup vs baseline: 1.1280x; 1.0488x over previous
//
#include <hip/hip_runtime.h>
#include <hip/hip_bf16.h>
#include <hip/hip_fp8.h>
#include <stdint.h>

#define B_   8
#define C_   512
#define NPIX 4096
#define VLDB 4160   // V row stride in BYTES: 65x64B (odd multiplier, r12 law)

typedef __attribute__((ext_vector_type(8))) short bf16x8;
typedef __attribute__((ext_vector_type(4))) float f32x4;

__device__ __forceinline__ uint16_t f2bf(float f) {
    union { float f; uint32_t u; } v; v.f = f;
    uint32_t u = v.u;
    return (uint16_t)((u + 0x7FFFu + ((u >> 16) & 1u)) >> 16);
}

__device__ __forceinline__ uint32_t pk2(float a, float b) {
    union { __hip_bfloat162 h; uint32_t u; } c;
    c.h = __float22bfloat162_rn(make_float2(a, b));
    return c.u;
}

// raw v_exp_f32 (2^x); inputs small and clamped.
__device__ __forceinline__ float fexp2(float x) {
#if __has_builtin(__builtin_amdgcn_exp2f)
    return __builtin_amdgcn_exp2f(x);
#else
    return exp2f(x);
#endif
}

template<bool HI>
__device__ __forceinline__ uint32_t pk_fp8(float a, float b, uint32_t old) {
#if __has_builtin(__builtin_amdgcn_cvt_pk_fp8_f32)
    return __builtin_amdgcn_cvt_pk_fp8_f32(a, b, old, HI);
#else
    union { __hip_fp8_storage_t s[4]; uint32_t u; } r; r.u = old;
    r.s[HI * 2 + 0] = __hip_cvt_float_to_fp8(a, __HIP_SATFINITE, __HIP_E4M3);
    r.s[HI * 2 + 1] = __hip_cvt_float_to_fp8(b, __HIP_SATFINITE, __HIP_E4M3);
    return r.u;
#endif
}
__device__ __forceinline__ uint8_t f2fp8(float a) {
#if __has_builtin(__builtin_amdgcn_cvt_pk_fp8_f32)
    uint32_t u = __builtin_amdgcn_cvt_pk_fp8_f32(a, 0.f, 0u, false);
    return (uint8_t)(u & 0xFF);
#else
    return __hip_cvt_float_to_fp8(a, __HIP_SATFINITE, __HIP_E4M3);
#endif
}

// j-permutation within a 64-elem row so one 16B/lane load covers both kk frags
__device__ __forceinline__ int perm64(int d) {
    return ((d >> 3) & 3) * 16 + ((d >> 5) << 3) + (d & 7);
}

// ---------------- W -> bf16 pre-convert (once) -----------------------------
__global__ __launch_bounds__(256, 4) void convw_kernel(
    const float* __restrict__ W, uint16_t* __restrict__ Wb)
{
    int i = (blockIdx.x * 256 + threadIdx.x) * 8;
    float4 a = *(const float4*)&W[i];
    float4 b = *(const float4*)&W[i + 4];
    union { bf16x8 v; uint32_t u[4]; } r;
    r.u[0] = pk2(a.x, a.y); r.u[1] = pk2(a.z, a.w);
    r.u[2] = pk2(b.x, b.y); r.u[3] = pk2(b.z, b.w);
    *(bf16x8*)&Wb[i] = r.v;
}

// ---------------- all projections fused: one block = one (n-tile, b) -------
// Stages x -> q, y -> k, z -> v(8 o-tiles) through one reused 64KB LDS tile.
// Replaces 3 serialized kernel launches (boundary+tail ~15us) with 1.
// q/k: bf16 out[b][n][o]; v: fp8 perm64 rows, stride VLDB, scale 64.
__global__ __launch_bounds__(256, 2) void proj_all_kernel(
    const float* __restrict__ x, const float* __restrict__ y,
    const float* __restrict__ z,
    const float* __restrict__ Wq, const float* __restrict__ bq,
    const float* __restrict__ Wk, const float* __restrict__ bk,
    const uint16_t* __restrict__ Wvb, const float* __restrict__ bv,
    uint16_t* __restrict__ qT, uint16_t* __restrict__ kT,
    uint8_t* __restrict__ vb)
{
    __shared__ char xt[64 * 1024];   // [n][c] bf16, byte = n*1024+2c ^ ((n&7)<<4)
    const int b  = blockIdx.y;
    const int n0 = blockIdx.x * 64;
    const int t = threadIdx.x, w = t >> 6, l = t & 63;
    const int l15 = l & 15, lg = l >> 4;

    auto stage = [&](const float* X) {
        const float* Xb = X + (size_t)b * C_ * NPIX + n0;
        for (int cc = 0; cc < C_; cc += 64) {
            #pragma unroll
            for (int i = 0; i < 16; i += 2) {
                int c = cc + w * 16 + i;
                float f0 = Xb[(size_t)c * NPIX + l];
                float f1 = Xb[(size_t)(c + 1) * NPIX + l];
                uint32_t pair = pk2(f0, f1);
                int byte = (l * 1024 + c * 2) ^ ((l & 7) << 4);
                *(uint32_t*)(xt + byte) = pair;
            }
        }
    };

    auto qkphase = [&](const float* W, const float* bias, float scale,
                       uint16_t* out) {
        f32x4 acc[4] = {};
        #pragma unroll 1
        for (int cc = 0; cc < C_; cc += 64) {
            #pragma unroll
            for (int kk = 0; kk < 2; kk++) {
                int o  = w * 16 + l15;
                int cb = cc + kk * 32 + lg * 8;
                float4 wa = *(const float4*)&W[(size_t)o * C_ + cb];
                float4 wb = *(const float4*)&W[(size_t)o * C_ + cb + 4];
                union { bf16x8 v; uint32_t u[4]; } afu;
                afu.u[0] = pk2(wa.x, wa.y); afu.u[1] = pk2(wa.z, wa.w);
                afu.u[2] = pk2(wb.x, wb.y); afu.u[3] = pk2(wb.z, wb.w);
                #pragma unroll
                for (int jt = 0; jt < 4; jt++) {
                    int n = jt * 16 + l15;
                    int byte = (n * 1024 + cb * 2) ^ ((n & 7) << 4);
                    bf16x8 bfr = *(bf16x8*)(xt + byte);
                    acc[jt] = __builtin_amdgcn_mfma_f32_16x16x32_bf16(afu.v, bfr, acc[jt], 0, 0, 0);
                }
            }
        }
        int og = w * 16 + lg * 4;
        #pragma unroll
        for (int jt = 0; jt < 4; jt++) {
            int n = n0 + jt * 16 + l15;
            #pragma unroll
            for (int r = 0; r < 4; r++) {
                float v = (acc[jt][r] + bias[og + r]) * scale;
                out[((size_t)b * NPIX + n) * 64 + og + r] = f2bf(v);
            }
        }
    };

    // q from x
    stage(x);
    __syncthreads();
    qkphase(Wq, bq, 1.4426950408889634f, qT);
    __syncthreads();
    // k from y
    stage(y);
    __syncthreads();
    qkphase(Wk, bk, 1.0f, kT);
    __syncthreads();
    // v from z: 8 o-tiles from the same staged tile
    stage(z);
    __syncthreads();
    #pragma unroll 1
    for (int o0 = 0; o0 < C_; o0 += 64) {
        f32x4 acc[4] = {};
        #pragma unroll 1
        for (int cc = 0; cc < C_; cc += 64) {
            #pragma unroll
            for (int kk = 0; kk < 2; kk++) {
                int o  = o0 + w * 16 + l15;
                int cb = cc + kk * 32 + lg * 8;
                bf16x8 af = *(const bf16x8*)&Wvb[(size_t)o * C_ + cb];
                #pragma unroll
                for (int jt = 0; jt < 4; jt++) {
                    int n = jt * 16 + l15;
                    int byte = (n * 1024 + cb * 2) ^ ((n & 7) << 4);
                    bf16x8 bfr = *(bf16x8*)(xt + byte);
                    acc[jt] = __builtin_amdgcn_mfma_f32_16x16x32_bf16(af, bfr, acc[jt], 0, 0, 0);
                }
            }
        }
        int og = o0 + w * 16 + lg * 4;
        #pragma unroll
        for (int jt = 0; jt < 4; jt++) {
            int j6 = jt * 16 + l15;
            int pos = perm64(j6);
            #pragma unroll
            for (int r = 0; r < 4; r++) {
                float v = (acc[jt][r] + bv[og + r]) * 64.0f;  // fp8 mid-range
                vb[((size_t)b * C_ + og + r) * (size_t)VLDB + (size_t)(n0 >> 6) * 64 + pos] = f2fp8(v);
            }
        }
    }
}

// ---------------- fused flash attention (r19, frozen) ----------------------
// 8-wave block owns q-tile x all 512 ch; softmax once; KVBLK=128 (32 steps);
// fp8 V+P, bf16 QK; lgkm-only barrier; at the L1-request equilibrium ~180us.
__global__ __launch_bounds__(512, 1) void attn_kernel(
    const uint16_t* __restrict__ qT, const uint16_t* __restrict__ kT,
    const uint8_t* __restrict__ vB, const float* __restrict__ X,
    const float* __restrict__ gamma_p, float* __restrict__ out)
{
    __shared__ char  Pl[3][64 * 128];   // P[i][j] fp8, byte=i*128+j ^ ((i&15)<<3)
    __shared__ float lsum[64][9];

    const int id = blockIdx.x;
    const int b  = id & 7;
    const int qt = id >> 3;
    const int i0 = qt * 64;

    const int t = threadIdx.x, w = t >> 6, l = t & 63;
    const int l15 = l & 15, lg = l >> 4;
    const int c0 = w * 64;

    auto barrier_lds = [&]() {
        asm volatile("s_waitcnt lgkmcnt(0)" ::: "memory");
        __builtin_amdgcn_s_barrier();
    };

    bf16x8 q8[4][2];
    #pragma unroll
    for (int it = 0; it < 4; it++)
        #pragma unroll
        for (int kk = 0; kk < 2; kk++)
            q8[it][kk] = *(const bf16x8*)&qT[((size_t)b * NPIX + i0 + it*16 + l15) * 64 + kk*32 + lg*8];

    f32x4 oacc[4][4] = {};
    float l_part[4] = {0.f, 0.f, 0.f, 0.f};

    const uint16_t* kTb = kT + (size_t)b * NPIX * 64;
    const uint8_t*  vBb = vB + ((size_t)b * C_ + c0) * (size_t)VLDB + lg * 16;
    const uint16_t* kROW = kTb + (size_t)(w * 16 + l15) * 64 + lg * 8;

    int vrowB[4];
    #pragma unroll
    for (int ct = 0; ct < 4; ct++) vrowB[ct] = (ct * 16 + l15) * VLDB;

    bf16x8 k8[2];
    ulong2 vreg[8];
    f32x4 s[4];

    auto loadK = [&](int step) {
        const uint16_t* p = kROW + (size_t)step * (128 * 64);
        k8[0] = *(const bf16x8*)p;
        k8[1] = *(const bf16x8*)(p + 32);
    };
    auto loadV = [&](int step) {
        const uint8_t* p = vBb + (size_t)step * 128;
        #pragma unroll
        for (int jh = 0; jh < 2; jh++)
            #pragma unroll
            for (int ct = 0; ct < 4; ct++)
                vreg[jh*4+ct] = *(const ulong2*)(p + vrowB[ct] + jh * 64);
    };
    auto QK = [&]() {
        #pragma unroll
        for (int it = 0; it < 4; it++) s[it] = f32x4{0.f, 0.f, 0.f, 0.f};
        __builtin_amdgcn_s_setprio(1);
        #pragma unroll
        for (int kk = 0; kk < 2; kk++)
            #pragma unroll
            for (int it = 0; it < 4; it++)
                s[it] = __builtin_amdgcn_mfma_f32_16x16x32_bf16(k8[kk], q8[it][kk], s[it], 0, 0, 0);
        __builtin_amdgcn_s_setprio(0);
    };
    auto PcomputeWrite = [&](char* Pn) {
        #pragma unroll
        for (int it = 0; it < 4; it++) {
            float e0 = fexp2(fminf(s[it][0], 60.f));
            float e1 = fexp2(fminf(s[it][1], 60.f));
            float e2 = fexp2(fminf(s[it][2], 60.f));
            float e3 = fexp2(fminf(s[it][3], 60.f));
            l_part[it] += (e0 + e1) + (e2 + e3);
            uint32_t p4 = pk_fp8<false>(e0, e1, 0u);
            p4 = pk_fp8<true>(e2, e3, p4);
            int i = it * 16 + l15;
            int byte = (i * 128 + w * 16 + lg * 4) ^ ((i & 15) << 3);
            *(uint32_t*)(Pn + byte) = p4;
        }
    };
    auto PV = [&](const char* P) {
        __builtin_amdgcn_s_setprio(1);
        #pragma unroll
        for (int jh = 0; jh < 2; jh++)
            #pragma unroll
            for (int kk = 0; kk < 2; kk++) {
                long pb[4];
                #pragma unroll
                for (int it = 0; it < 4; it++) {
                    int i = it * 16 + l15;
                    int byte = (i * 128 + jh * 64 + kk * 32 + lg * 8) ^ ((i & 15) << 3);
                    pb[it] = *(const long*)(P + byte);
                }
                #pragma unroll
                for (int ct = 0; ct < 4; ct++) {
                    long v8 = (long)(kk ? vreg[jh*4+ct].y : vreg[jh*4+ct].x);
                    #pragma unroll
                    for (int it = 0; it < 4; it++)
                        oacc[ct][it] = __builtin_amdgcn_mfma_f32_16x16x32_fp8_fp8(v8, pb[it], oacc[ct][it], 0, 0, 0);
                }
            }
        __builtin_amdgcn_s_setprio(0);
    };

    // ---- prologue ----
    loadK(0);
    loadV(0);
    QK();
    loadK(1);
    PcomputeWrite(Pl[0]);
    QK();
    loadK(2);
    PcomputeWrite(Pl[1]);

    char* Pprev = Pl[0];
    char* Pcur  = Pl[1];
    char* Pnext = Pl[2];

    #pragma unroll 1
    for (int jt_ = 1; jt_ < 32; ++jt_) {
        barrier_lds();
        PV(Pprev);
        loadV(jt_);
        if (jt_ < 31) {
            QK();
            if (jt_ < 30) loadK(jt_ + 2);
            PcomputeWrite(Pnext);
        }
        char* tmp = Pprev; Pprev = Pcur; Pcur = Pnext; Pnext = tmp;
    }
    barrier_lds();
    PV(Pprev);

    #pragma unroll
    for (int it = 0; it < 4; it++) {
        float v = l_part[it];
        v += __shfl_xor(v, 16);
        v += __shfl_xor(v, 32);
        if (lg == 0) lsum[it * 16 + l15][w] = v;
    }
    __syncthreads();

    float gamma = gamma_p[0];
    float rl[4];
    #pragma unroll
    for (int it = 0; it < 4; it++) {
        int i = it * 16 + l15;
        float lt = ((lsum[i][0] + lsum[i][1]) + (lsum[i][2] + lsum[i][3]))
                 + ((lsum[i][4] + lsum[i][5]) + (lsum[i][6] + lsum[i][7]));
        rl[it] = 1.0f / (64.0f * lt);
    }
    #pragma unroll
    for (int ct = 0; ct < 4; ct++)
        #pragma unroll
        for (int r = 0; r < 4; r++) {
            int c = c0 + ct * 16 + lg * 4 + r;
            #pragma unroll
            for (int it = 0; it < 4; it++) {
                int n = i0 + it * 16 + l15;
                size_t idx = ((size_t)b * C_ + c) * NPIX + n;
                out[idx] = gamma * (oacc[ct][it][r] * rl[it]) + X[idx];
            }
        }
}

extern "C" void kernel_launch(void* const* d_in, const int* in_sizes, int n_in,
                              void* d_out, int out_size, void* d_ws, size_t ws_size,
                              hipStream_t stream) {
    const float* x     = (const float*)d_in[0];
    const float* y     = (const float*)d_in[1];
    const float* z     = (const float*)d_in[2];
    const float* Wq    = (const float*)d_in[3];
    const float* bq    = (const float*)d_in[4];
    const float* Wk    = (const float*)d_in[5];
    const float* bk    = (const float*)d_in[6];
    const float* Wv    = (const float*)d_in[7];
    const float* bv    = (const float*)d_in[8];
    const float* gamma = (const float*)d_in[9];
    float* out = (float*)d_out;

    uint16_t* qT  = (uint16_t*)d_ws;                        // [8][4096][64] bf16
    uint16_t* kT  = qT + (size_t)B_ * NPIX * 64;            // [8][4096][64] bf16
    uint8_t*  vb  = (uint8_t*)(kT + (size_t)B_ * NPIX * 64);// [8][512] x VLDB, fp8
    uint16_t* Wvb = (uint16_t*)(vb + (size_t)B_ * C_ * VLDB); // [512][512] bf16

    convw_kernel<<<dim3(128), dim3(256), 0, stream>>>(Wv, Wvb);
    proj_all_kernel<<<dim3(64, 8), dim3(256), 0, stream>>>(
        x, y, z, Wq, bq, Wk, bk, Wvb, bv, qT, kT, vb);
    attn_kernel<<<dim3(512), dim3(512), 0, stream>>>(qT, kT, vb, x, gamma, out);
}